// Round 11
// baseline (679.249 us; speedup 1.0000x reference)
//
#include <hip/hip_runtime.h>

typedef unsigned short u16;
typedef __attribute__((ext_vector_type(4))) short short4v;
typedef __attribute__((ext_vector_type(8))) short short8v;
typedef __attribute__((ext_vector_type(4))) unsigned short ushort4v;
typedef __attribute__((ext_vector_type(4))) float float4v;

#define GLOAD16(ldsp, gp)                                                      \
  __builtin_amdgcn_global_load_lds(                                            \
      (const __attribute__((address_space(1))) unsigned int*)(gp),             \
      (__attribute__((address_space(3))) unsigned int*)(ldsp), 16, 0, 0)

__device__ __forceinline__ u16 f2bf(float f) {
  union { float f; unsigned u; } v; v.f = f;
  unsigned r = v.u + 0x7fffu + ((v.u >> 16) & 1u);
  return (u16)(r >> 16);
}
__device__ __forceinline__ float bf2f(u16 h) {
  union { unsigned u; float f; } v; v.u = ((unsigned)h) << 16;
  return v.f;
}
__device__ __forceinline__ float fmap(float x) { return x > 0.f ? x + 1.f : __expf(x); }

// k-permutation: storage position 8g+j (within a 32-block) holds k = 4g + (j<4? j : 12+j).
__device__ __forceinline__ int permp(int k) {
  const int r5 = k & 31;
  const int p = (r5 < 16) ? ((r5 >> 2) * 8 + (r5 & 3))
                          : (((r5 - 16) >> 2) * 8 + 4 + ((r5 - 16) & 3));
  return (k & ~31) + p;
}

// ======================= 2-phase core (kvpart only) ==========================
__device__ __forceinline__ void gemm_core(
    const u16* __restrict__ A, int lda, const u16* __restrict__ B, int ldb,
    int m0, int n0, int k0, int nsteps, u16* Al, u16* Bl, float4v acc[4][4]) {
  const int lane = threadIdx.x & 63;
  const int wid  = threadIdx.x >> 6;
  const int wr = wid >> 1, wc = wid & 1;
  const int sr = lane >> 3;
  const int sc = ((lane & 7) ^ (lane >> 3)) * 8;
  const int swz = (lane & 7) << 4;
  const int g4 = 4 * (lane >> 4);
  for (int kt = 0; kt < nsteps; ++kt) {
    const int kb = k0 + kt * 64;
#pragma unroll
    for (int jj = 0; jj < 4; ++jj) {
      const int rb = wid * 8 + jj * 32;
      GLOAD16(Al + rb * 64, A + (size_t)(m0 + rb + sr) * lda + kb + sc);
      GLOAD16(Bl + rb * 64, B + (size_t)(n0 + rb + sr) * ldb + kb + sc);
    }
    __syncthreads();
#pragma unroll
    for (int kk = 0; kk < 64; kk += 32) {
      const int c0 = 2 * (kk + g4);
      short8v af[4], bfr[4];
#pragma unroll
      for (int i = 0; i < 4; ++i) {
        const char* pa = (const char*)(Al + (wr * 64 + i * 16 + (lane & 15)) * 64);
        short4v a0 = *(const short4v*)(pa + (c0 ^ swz));
        short4v a1 = *(const short4v*)(pa + ((c0 + 32) ^ swz));
        af[i] = __builtin_shufflevector(a0, a1, 0, 1, 2, 3, 4, 5, 6, 7);
        const char* pb = (const char*)(Bl + (wc * 64 + i * 16 + (lane & 15)) * 64);
        short4v b0 = *(const short4v*)(pb + (c0 ^ swz));
        short4v b1 = *(const short4v*)(pb + ((c0 + 32) ^ swz));
        bfr[i] = __builtin_shufflevector(b0, b1, 0, 1, 2, 3, 4, 5, 6, 7);
      }
#pragma unroll
      for (int i = 0; i < 4; ++i)
#pragma unroll
        for (int j = 0; j < 4; ++j)
          acc[i][j] = __builtin_amdgcn_mfma_f32_16x16x32_bf16(af[i], bfr[j], acc[i][j], 0, 0, 0);
    }
    __syncthreads();
  }
}

#define ZERO_ACC4(acc)                                           \
  _Pragma("unroll") for (int i_ = 0; i_ < 4; ++i_)               \
  _Pragma("unroll") for (int j_ = 0; j_ < 4; ++j_)               \
      acc[i_][j_] = (float4v){0.f, 0.f, 0.f, 0.f};

// ============ 256x256 8-phase core, SINGLE barrier per phase ================
// (structure identical to round 10; see WAR/RAW audit there)
#define FRAG(tile, row, slog)                                                  \
  (*(const short8v*)((const char*)(tile) + (row) * 128 + ((((slog) ^ ((row) & 7))) * 16)))

#define LBAR()                                                                 \
  do { asm volatile("s_waitcnt lgkmcnt(0)" ::: "memory");                      \
       __builtin_amdgcn_s_barrier();                                           \
       __builtin_amdgcn_sched_barrier(0); asm volatile("" ::: "memory"); } while (0)

#define WAITVM6() asm volatile("s_waitcnt vmcnt(6)" ::: "memory")
#define WAITVM0() asm volatile("s_waitcnt vmcnt(0)" ::: "memory")

#define READA(Asrc, m0)                                                        \
  aF0  = FRAG(Asrc, wr * 128 + (m0) * 16 + l15, g);                            \
  aF0k = FRAG(Asrc, wr * 128 + (m0) * 16 + l15, 4 + g);                        \
  aF1  = FRAG(Asrc, wr * 128 + (m0) * 16 + 16 + l15, g);                       \
  aF1k = FRAG(Asrc, wr * 128 + (m0) * 16 + 16 + l15, 4 + g);

#define READB(Bsrc)                                                            \
  _Pragma("unroll") for (int j_ = 0; j_ < 4; ++j_) {                           \
    bF[0][j_] = FRAG(Bsrc, wc * 64 + j_ * 16 + l15, g);                        \
    bF[1][j_] = FRAG(Bsrc, wc * 64 + j_ * 16 + l15, 4 + g);                    \
  }

#define MFMA16(m0)                                                             \
  __builtin_amdgcn_s_setprio(1);                                               \
  _Pragma("unroll") for (int j_ = 0; j_ < 4; ++j_) {                           \
    acc[(m0)][j_]     = __builtin_amdgcn_mfma_f32_16x16x32_bf16(aF0,  bF[0][j_], acc[(m0)][j_], 0, 0, 0);     \
    acc[(m0) + 1][j_] = __builtin_amdgcn_mfma_f32_16x16x32_bf16(aF1,  bF[0][j_], acc[(m0) + 1][j_], 0, 0, 0); \
  }                                                                            \
  _Pragma("unroll") for (int j_ = 0; j_ < 4; ++j_) {                           \
    acc[(m0)][j_]     = __builtin_amdgcn_mfma_f32_16x16x32_bf16(aF0k, bF[1][j_], acc[(m0)][j_], 0, 0, 0);     \
    acc[(m0) + 1][j_] = __builtin_amdgcn_mfma_f32_16x16x32_bf16(aF1k, bF[1][j_], acc[(m0) + 1][j_], 0, 0, 0); \
  }                                                                            \
  __builtin_amdgcn_s_setprio(0);

#define STA(bufptr, c, t) GLOAD16((bufptr) + (c) * 4096 + ldsw, A + (size_t)(c) * 64 * 1024 + (t) * 64 + poff)
#define STB(bufptr, c, t) GLOAD16((bufptr) + (c) * 4096 + ldsw, B + (size_t)(c) * 64 * 1024 + (t) * 64 + poff)

__device__ __forceinline__ void gemm8_core(
    const u16* __restrict__ A, const u16* __restrict__ B,
    u16* As0, u16* As1, u16* Bs0, u16* Bs1, float4v acc[8][4]) {
  const int tid = threadIdx.x;
  const int lane = tid & 63, wid = tid >> 6;
  const int wr = wid >> 2, wc = wid & 3;
  const int l15 = lane & 15, g = lane >> 4;
  const int poff = (wid * 8 + (lane >> 3)) * 1024 + ((lane & 7) ^ ((lane >> 3) & 7)) * 8;
  const int ldsw = wid * 512;

  STB(Bs0, 0, 0); STB(Bs0, 1, 0); STB(Bs0, 2, 0); STB(Bs0, 3, 0);
  STA(As0, 0, 0); STA(As0, 1, 0); STA(As0, 2, 0); STA(As0, 3, 0);
  STB(Bs1, 0, 1); STB(Bs1, 1, 1); STB(Bs1, 2, 1); STB(Bs1, 3, 1);
  STA(As1, 0, 1); STA(As1, 2, 1);
  WAITVM6();
  __builtin_amdgcn_s_barrier();
  __builtin_amdgcn_sched_barrier(0);

  for (int i = 0; i < 8; ++i) {
    const int t1 = 2 * i + 1, t2 = 2 * i + 2, t3 = 2 * i + 3;
    const bool more = (i < 7);
    short8v bF[2][4];
    short8v aF0, aF0k, aF1, aF1k;
    // PH1
    READB(Bs0); READA(As0, 0);
    STA(As1, 1, t1); STA(As1, 3, t1);
    LBAR(); MFMA16(0);
    // PH2
    READA(As0, 2);
    if (more) { STB(Bs0, 0, t2); STB(Bs0, 1, t2); }
    LBAR(); MFMA16(2);
    // PH3
    READA(As0, 4);
    if (more) { STB(Bs0, 2, t2); STB(Bs0, 3, t2); }
    LBAR(); MFMA16(4);
    // PH4
    READA(As0, 6);
    if (more) { STA(As0, 0, t2); STA(As0, 2, t2); }
    if (more) { WAITVM6(); } else { WAITVM0(); }
    LBAR(); MFMA16(6);
    // PH5
    READB(Bs1); READA(As1, 0);
    if (more) { STA(As0, 1, t2); STA(As0, 3, t2); }
    LBAR(); MFMA16(0);
    // PH6
    READA(As1, 2);
    if (more) { STB(Bs1, 0, t3); STB(Bs1, 1, t3); }
    LBAR(); MFMA16(2);
    // PH7
    READA(As1, 4);
    if (more) { STB(Bs1, 2, t3); STB(Bs1, 3, t3); }
    LBAR(); MFMA16(4);
    // PH8
    READA(As1, 6);
    if (more) { STA(As1, 0, t3); STA(As1, 2, t3); }
    if (more) { WAITVM6(); }
    LBAR(); MFMA16(6);
  }
}

#define ZERO_ACC8(acc)                                           \
  _Pragma("unroll") for (int i_ = 0; i_ < 8; ++i_)               \
  _Pragma("unroll") for (int j_ = 0; j_ < 4; ++j_)               \
      acc[i_][j_] = (float4v){0.f, 0.f, 0.f, 0.f};

// ---------------------------------------------------------------------------
__global__ void __launch_bounds__(256) k_conv(const float* __restrict__ in,
                                              u16* __restrict__ out) {
  const int i = blockIdx.x * 256 + threadIdx.x;
  float4v v = __builtin_nontemporal_load(&((const float4v*)in)[i]);  // x read once
  const int row = i >> 8;
  const int c = (i & 255) * 4;
  ushort4v o;
  o[0] = f2bf(v[0]); o[1] = f2bf(v[1]); o[2] = f2bf(v[2]); o[3] = f2bf(v[3]);
  *(ushort4v*)(out + (size_t)row * 1024 + permp(c)) = o;
}

// ---------------------------------------------------------------------------
__global__ void __launch_bounds__(256) k_transpose(const float* __restrict__ in,
                                                   u16* __restrict__ out, int R, int C) {
  __shared__ u16 tile[64][65];
  const int nbc = C >> 6;
  const int bc = blockIdx.x % nbc, br = blockIdx.x / nbc;
  const int r0 = br * 64, c0 = bc * 64;
  const int t = threadIdx.x;
  const int lr = t >> 4;
  const int lc = (t & 15) * 4;
#pragma unroll
  for (int p = 0; p < 4; ++p) {
    const int r = p * 16 + lr;
    float4v v = *(const float4v*)(in + (size_t)(r0 + r) * C + c0 + lc);
    tile[r][lc + 0] = f2bf(v[0]); tile[r][lc + 1] = f2bf(v[1]);
    tile[r][lc + 2] = f2bf(v[2]); tile[r][lc + 3] = f2bf(v[3]);
  }
  __syncthreads();
#pragma unroll
  for (int p = 0; p < 4; ++p) {
    const int c = p * 16 + lr;
    ushort4v o;
    o[0] = tile[lc + 0][c]; o[1] = tile[lc + 1][c];
    o[2] = tile[lc + 2][c]; o[3] = tile[lc + 3][c];
    *(ushort4v*)(out + (size_t)(c0 + c) * R + permp(r0 + lc)) = o;
  }
}

// ---------------------------------------------------------------------------
// GEMM1 (8-phase): h1 = x@W1 + b1 -> q / k_t / non_att(fp32, NT store)
// mt-FASTEST ordering: concurrent blocks on an XCD share one B panel (L2-hot),
// A (x, L3-resident) streams.
// ---------------------------------------------------------------------------
__global__ void __launch_bounds__(512, 2) k_gemm1n(
    const u16* __restrict__ xb, const u16* __restrict__ w1t,
    const float* __restrict__ bias1, u16* __restrict__ qbuf,
    u16* __restrict__ ktb, float* __restrict__ dout) {
  __shared__ u16 As[2][16384], Bs[2][16384];
  const int wg = (blockIdx.x & 7) * 192 + (blockIdx.x >> 3);   // 1536 wgs
  const int mt = wg & 127, nt = wg >> 7;                       // mt-fastest
  float4v acc[8][4];
  ZERO_ACC8(acc);
  gemm8_core(xb + (size_t)mt * 256 * 1024, w1t + (size_t)nt * 256 * 1024,
             As[0], As[1], Bs[0], Bs[1], acc);
  const int lane = threadIdx.x & 63, wid = threadIdx.x >> 6;
  const int wr = wid >> 2, wc = wid & 3;
  const int l15 = lane & 15, g = lane >> 4;
  const int region = nt >> 2;
#pragma unroll
  for (int m = 0; m < 8; ++m) {
    const int rb = mt * 256 + wr * 128 + m * 16 + 4 * g;
#pragma unroll
    for (int j = 0; j < 4; ++j) {
      const int cg = nt * 256 + wc * 64 + j * 16 + l15;
      const float bia = bias1[cg];
      if (region == 0) {
#pragma unroll
        for (int r = 0; r < 4; ++r)
          qbuf[(size_t)(rb + r) * 1024 + cg] = f2bf(fmap(acc[m][j][r] + bia));
      } else if (region == 1) {
        const int rc = cg - 1024;
        ushort4v pk;
#pragma unroll
        for (int r = 0; r < 4; ++r) pk[r] = f2bf(fmap(acc[m][j][r] + bia));
        *(ushort4v*)(ktb + (size_t)rc * 32768 + rb) = pk;
      } else {
        const int rc = cg - 2048;
        // non_att: 128 MB fp32 re-read only at the very end -> nontemporal
#pragma unroll
        for (int r = 0; r < 4; ++r)
          __builtin_nontemporal_store(acc[m][j][r] + bia,
                                      &dout[(size_t)(rb + r) * 1024 + rc]);
      }
    }
  }
}

// ---------------------------------------------------------------------------
// GEMM2 (8-phase): v = x@Wv + bv -> v_t [dim][N]   (mt-fastest ordering)
// ---------------------------------------------------------------------------
__global__ void __launch_bounds__(512, 2) k_gemm2n(
    const u16* __restrict__ xb, const u16* __restrict__ wvt,
    const float* __restrict__ biasv, u16* __restrict__ vtb) {
  __shared__ u16 As[2][16384], Bs[2][16384];
  const int wg = (blockIdx.x & 7) * 64 + (blockIdx.x >> 3);    // 512 wgs
  const int mt = wg & 127, nt = wg >> 7;                       // mt-fastest
  float4v acc[8][4];
  ZERO_ACC8(acc);
  gemm8_core(xb + (size_t)mt * 256 * 1024, wvt + (size_t)nt * 256 * 1024,
             As[0], As[1], Bs[0], Bs[1], acc);
  const int lane = threadIdx.x & 63, wid = threadIdx.x >> 6;
  const int wr = wid >> 2, wc = wid & 3;
  const int l15 = lane & 15, g = lane >> 4;
#pragma unroll
  for (int m = 0; m < 8; ++m) {
    const int rb = mt * 256 + wr * 128 + m * 16 + 4 * g;
#pragma unroll
    for (int j = 0; j < 4; ++j) {
      const int cg = nt * 256 + wc * 64 + j * 16 + l15;
      const float bia = biasv[cg];
      ushort4v pk;
#pragma unroll
      for (int r = 0; r < 4; ++r) pk[r] = f2bf(acc[m][j][r] + bia);
      *(ushort4v*)(vtb + (size_t)cg * 32768 + rb) = pk;
    }
  }
}

// ---------------------------------------------------------------------------
// kv partials (bf16) + fused k_sum partials. Per (head, K-chunk of 512):
// ---------------------------------------------------------------------------
__global__ void __launch_bounds__(256) k_kvpart(
    const u16* __restrict__ ktb, const u16* __restrict__ vtb,
    u16* __restrict__ part, float* __restrict__ kspart) {
  __shared__ u16 Al[128 * 64], Bl[128 * 64];
  const int h = blockIdx.x >> 6, ch = blockIdx.x & 63;
  float4v acc[4][4];
  ZERO_ACC4(acc);
  gemm_core(ktb + (size_t)h * 128 * 32768, 32768,
            vtb + (size_t)h * 128 * 32768, 32768, 0, 0, ch * 512, 8, Al, Bl, acc);
  u16* o = part + (size_t)(h * 64 + ch) * 16384;
  const int lane = threadIdx.x & 63, wid = threadIdx.x >> 6;
  const int wr = wid >> 1, wc = wid & 1;
#pragma unroll
  for (int i = 0; i < 4; ++i) {
    const int rb = wr * 64 + i * 16 + 4 * (lane >> 4);
#pragma unroll
    for (int j = 0; j < 4; ++j) {
      const int cg = wc * 64 + j * 16 + (lane & 15);
#pragma unroll
      for (int r = 0; r < 4; ++r) o[(size_t)(rb + r) * 128 + cg] = f2bf(acc[i][j][r]);
    }
  }
  // fused k_sum partial: rows are L2/L3-hot (just staged above).
  float* ksp = kspart + (size_t)(h * 64 + ch) * 128;
#pragma unroll
  for (int it = 0; it < 8; ++it) {
    const int row = it * 16 + wid * 4 + (lane >> 4);
    const u16* src = ktb + (size_t)(h * 128 + row) * 32768 + ch * 512 + (lane & 15) * 32;
    float s = 0.f;
#pragma unroll
    for (int u = 0; u < 4; ++u) {
      short8v v = *(const short8v*)(src + u * 8);
#pragma unroll
      for (int e = 0; e < 8; ++e) s += bf2f((u16)v[e]);
    }
#pragma unroll
    for (int m = 1; m < 16; m <<= 1) s += __shfl_xor(s, m, 64);
    if ((lane & 15) == 0) ksp[row] = s;
  }
}

// ---------------------------------------------------------------------------
__global__ void __launch_bounds__(128) k_kvred(const u16* __restrict__ part,
                                               const float* __restrict__ kspart,
                                               u16* __restrict__ kvt,
                                               float* __restrict__ ksum) {
  const int b = blockIdx.x;
  const int h = b >> 7, kd = b & 127;
  const int vd = threadIdx.x;
  const u16* p = part + (size_t)h * 64 * 16384 + (size_t)kd * 128 + vd;
  float s = 0.f;
#pragma unroll
  for (int c = 0; c < 64; ++c) s += bf2f(p[(size_t)c * 16384]);
  kvt[(size_t)(h * 128 + vd) * 128 + kd] = f2bf(s);
  __shared__ float red[64];
  if (vd < 64) red[vd] = kspart[(size_t)(h * 64 + vd) * 128 + kd];
  __syncthreads();
  if (vd < 32) red[vd] += red[vd + 32];
  __syncthreads();
  if (vd == 0) {
    float t = 0.f;
#pragma unroll
    for (int c = 0; c < 32; ++c) t += red[c];
    ksum[h * 128 + kd] = t;
  }
}

// ---------------------------------------------------------------------------
// att = (q @ kv) / (q . k_sum); writes att k-PERMUTED (consumed by gemmo)
// ---------------------------------------------------------------------------
__global__ void __launch_bounds__(256) k_attn(
    const u16* __restrict__ q, const u16* __restrict__ kvt,
    const float* __restrict__ ksum, u16* __restrict__ att) {
  __shared__ u16 qlds[128 * 128];
  __shared__ u16 blds[128 * 128];
  __shared__ float ksl[128];
  __shared__ float qkl[128];
  const int b = blockIdx.x;
  const int h = b >> 8, nt = b & 255;
  const int n0 = nt * 128;
  const int tid = threadIdx.x, lane = tid & 63, wid = tid >> 6;
  const int wr = wid >> 1, wc = wid & 1;
  const int sr = lane >> 4;
#pragma unroll
  for (int jj = 0; jj < 8; ++jj) {
    const int rb = wid * 32 + jj * 4;
    const int srcslot = (lane & 15) ^ ((rb + (lane >> 4)) & 15);
    GLOAD16(qlds + rb * 128, q + (size_t)(n0 + rb + sr) * 1024 + h * 128 + srcslot * 8);
    GLOAD16(blds + rb * 128, kvt + (size_t)(h * 128 + rb + sr) * 128 + srcslot * 8);
  }
  if (tid < 128) ksl[tid] = ksum[h * 128 + tid];
  __syncthreads();
  if (tid < 128) {
    float s = 0.f;
    const int rsw = tid & 15;
#pragma unroll
    for (int ii = 0; ii < 16; ++ii) {
      const int slot = ii ^ rsw;
      short8v v = *(const short8v*)((const char*)qlds + tid * 256 + slot * 16);
#pragma unroll
      for (int e = 0; e < 8; ++e) s += bf2f((u16)v[e]) * ksl[ii * 8 + e];
    }
    qkl[tid] = (s == 0.f) ? 1e-5f : s;
  }
  float4v acc[4][4];
  ZERO_ACC4(acc);
  const int swz = (lane & 15) << 4;
  const int g4 = 4 * (lane >> 4);
#pragma unroll
  for (int kk = 0; kk < 128; kk += 32) {
    const int c0 = 2 * (kk + g4);
    short8v af[4], bfr[4];
#pragma unroll
    for (int i = 0; i < 4; ++i) {
      const char* pa = (const char*)(qlds + (wr * 64 + i * 16 + (lane & 15)) * 128);
      short4v a0 = *(const short4v*)(pa + (c0 ^ swz));
      short4v a1 = *(const short4v*)(pa + ((c0 + 32) ^ swz));
      af[i] = __builtin_shufflevector(a0, a1, 0, 1, 2, 3, 4, 5, 6, 7);
      const char* pb = (const char*)(blds + (wc * 64 + i * 16 + (lane & 15)) * 128);
      short4v b0 = *(const short4v*)(pb + (c0 ^ swz));
      short4v b1 = *(const short4v*)(pb + ((c0 + 32) ^ swz));
      bfr[i] = __builtin_shufflevector(b0, b1, 0, 1, 2, 3, 4, 5, 6, 7);
    }
#pragma unroll
    for (int i = 0; i < 4; ++i)
#pragma unroll
      for (int j = 0; j < 4; ++j)
        acc[i][j] = __builtin_amdgcn_mfma_f32_16x16x32_bf16(af[i], bfr[j], acc[i][j], 0, 0, 0);
  }
  __syncthreads();
#pragma unroll
  for (int i = 0; i < 4; ++i) {
    const int rl = wr * 64 + i * 16 + 4 * (lane >> 4);
#pragma unroll
    for (int j = 0; j < 4; ++j) {
      const int cl = wc * 64 + j * 16 + (lane & 15);
      const int pc = permp(h * 128 + cl);
#pragma unroll
      for (int r = 0; r < 4; ++r) {
        const float v = acc[i][j][r] / qkl[rl + r];
        att[(size_t)(n0 + rl + r) * 1024 + pc] = f2bf(v);
      }
    }
  }
}

// ---------------------------------------------------------------------------
// GEMMo (8-phase): out = non_att(in d_out) + att@Wo + bo  (NT final store)
// mt-fastest ordering.
// ---------------------------------------------------------------------------
__global__ void __launch_bounds__(512, 2) k_gemmon(
    const u16* __restrict__ attb, const u16* __restrict__ wot,
    const float* __restrict__ biaso, float* __restrict__ dout) {
  __shared__ u16 As[2][16384], Bs[2][16384];
  const int wg = (blockIdx.x & 7) * 64 + (blockIdx.x >> 3);    // 512 wgs
  const int mt = wg & 127, nt = wg >> 7;                       // mt-fastest
  float4v acc[8][4];
  ZERO_ACC8(acc);
  gemm8_core(attb + (size_t)mt * 256 * 1024, wot + (size_t)nt * 256 * 1024,
             As[0], As[1], Bs[0], Bs[1], acc);
  const int lane = threadIdx.x & 63, wid = threadIdx.x >> 6;
  const int wr = wid >> 2, wc = wid & 3;
  const int l15 = lane & 15, g = lane >> 4;
#pragma unroll
  for (int m = 0; m < 8; ++m) {
    const int rb = mt * 256 + wr * 128 + m * 16 + 4 * g;
#pragma unroll
    for (int j = 0; j < 4; ++j) {
      const int cg = nt * 256 + wc * 64 + j * 16 + l15;
      const float bia = biaso[cg];
#pragma unroll
      for (int r = 0; r < 4; ++r) {
        const size_t idx = (size_t)(rb + r) * 1024 + cg;
        const float v = dout[idx] + acc[m][j][r] + bia;
        __builtin_nontemporal_store(v, &dout[idx]);
      }
    }
  }
}

// ---------------------------------------------------------------------------
extern "C" void kernel_launch(void* const* d_in, const int* in_sizes, int n_in,
                              void* d_out, int out_size, void* d_ws, size_t ws_size,
                              hipStream_t stream) {
  const float* x  = (const float*)d_in[0];
  const float* W1 = (const float*)d_in[1];
  const float* b1 = (const float*)d_in[2];
  const float* Wv = (const float*)d_in[3];
  const float* bv = (const float*)d_in[4];
  const float* Wo = (const float*)d_in[5];
  const float* bo = (const float*)d_in[6];
  float* out = (float*)d_out;

  const size_t N = 32768;
  u16* xb   = (u16*)d_ws;                       // x bf16 perm-k [N][1024]
  u16* qb   = xb  + N * 1024;                   // q (then att, perm-k)
  u16* ktb  = qb  + N * 1024;                   // k_t [8*128][N]
  u16* vtb  = ktb + N * 1024;                   // v_t [8*128][N]
  u16* wcat = vtb + N * 1024;                   // [W1|Wv]^T perm-k [4096][1024]
  u16* wot  = wcat + (size_t)4096 * 1024;       // Wo^T perm-k
  u16* part = wot + (size_t)1024 * 1024;        // kv partials bf16 [8][64][16384]
  u16* kvt  = part + (size_t)8 * 64 * 16384;    // kv_t [h][vd][kd]
  float* ksum = (float*)(kvt + (size_t)8 * 16384);    // [8][128]
  float* kspart = ksum + 1024;                        // [8][64][128]

  k_conv<<<32768, 256, 0, stream>>>(x, xb);
  k_transpose<<<768, 256, 0, stream>>>(W1, wcat, 1024, 3072);
  k_transpose<<<256, 256, 0, stream>>>(Wv, wcat + (size_t)3072 * 1024, 1024, 1024);
  k_transpose<<<256, 256, 0, stream>>>(Wo, wot, 1024, 1024);
  k_gemm1n<<<1536, 512, 0, stream>>>(xb, wcat, b1, qb, ktb, out);
  k_gemm2n<<<512, 512, 0, stream>>>(xb, wcat + (size_t)3072 * 1024, bv, vtb);
  k_kvpart<<<512, 256, 0, stream>>>(ktb, vtb, part, kspart);
  k_kvred<<<1024, 128, 0, stream>>>(part, kspart, kvt, ksum);
  k_attn<<<2048, 256, 0, stream>>>(qb, kvt, ksum, qb);
  k_gemmon<<<512, 512, 0, stream>>>(qb, wot, bo, out);
}

// Round 12
// 564.028 us; speedup vs baseline: 1.2043x; 1.2043x over previous
//
#include <hip/hip_runtime.h>

typedef unsigned short u16;
typedef __attribute__((ext_vector_type(4))) short short4v;
typedef __attribute__((ext_vector_type(8))) short short8v;
typedef __attribute__((ext_vector_type(4))) unsigned short ushort4v;
typedef __attribute__((ext_vector_type(4))) float float4v;

#define GLOAD16(ldsp, gp)                                                      \
  __builtin_amdgcn_global_load_lds(                                            \
      (const __attribute__((address_space(1))) unsigned int*)(gp),             \
      (__attribute__((address_space(3))) unsigned int*)(ldsp), 16, 0, 0)

__device__ __forceinline__ u16 f2bf(float f) {
  union { float f; unsigned u; } v; v.f = f;
  unsigned r = v.u + 0x7fffu + ((v.u >> 16) & 1u);
  return (u16)(r >> 16);
}
__device__ __forceinline__ float bf2f(u16 h) {
  union { unsigned u; float f; } v; v.u = ((unsigned)h) << 16;
  return v.f;
}
__device__ __forceinline__ float fmap(float x) { return x > 0.f ? x + 1.f : __expf(x); }

// k-permutation: storage position 8g+j (within a 32-block) holds k = 4g + (j<4? j : 12+j).
__device__ __forceinline__ int permp(int k) {
  const int r5 = k & 31;
  const int p = (r5 < 16) ? ((r5 >> 2) * 8 + (r5 & 3))
                          : (((r5 - 16) >> 2) * 8 + 4 + ((r5 - 16) & 3));
  return (k & ~31) + p;
}

// ======================= 2-phase core (kvpart only) ==========================
__device__ __forceinline__ void gemm_core(
    const u16* __restrict__ A, int lda, const u16* __restrict__ B, int ldb,
    int m0, int n0, int k0, int nsteps, u16* Al, u16* Bl, float4v acc[4][4]) {
  const int lane = threadIdx.x & 63;
  const int wid  = threadIdx.x >> 6;
  const int wr = wid >> 1, wc = wid & 1;
  const int sr = lane >> 3;
  const int sc = ((lane & 7) ^ (lane >> 3)) * 8;
  const int swz = (lane & 7) << 4;
  const int g4 = 4 * (lane >> 4);
  for (int kt = 0; kt < nsteps; ++kt) {
    const int kb = k0 + kt * 64;
#pragma unroll
    for (int jj = 0; jj < 4; ++jj) {
      const int rb = wid * 8 + jj * 32;
      GLOAD16(Al + rb * 64, A + (size_t)(m0 + rb + sr) * lda + kb + sc);
      GLOAD16(Bl + rb * 64, B + (size_t)(n0 + rb + sr) * ldb + kb + sc);
    }
    __syncthreads();
#pragma unroll
    for (int kk = 0; kk < 64; kk += 32) {
      const int c0 = 2 * (kk + g4);
      short8v af[4], bfr[4];
#pragma unroll
      for (int i = 0; i < 4; ++i) {
        const char* pa = (const char*)(Al + (wr * 64 + i * 16 + (lane & 15)) * 64);
        short4v a0 = *(const short4v*)(pa + (c0 ^ swz));
        short4v a1 = *(const short4v*)(pa + ((c0 + 32) ^ swz));
        af[i] = __builtin_shufflevector(a0, a1, 0, 1, 2, 3, 4, 5, 6, 7);
        const char* pb = (const char*)(Bl + (wc * 64 + i * 16 + (lane & 15)) * 64);
        short4v b0 = *(const short4v*)(pb + (c0 ^ swz));
        short4v b1 = *(const short4v*)(pb + ((c0 + 32) ^ swz));
        bfr[i] = __builtin_shufflevector(b0, b1, 0, 1, 2, 3, 4, 5, 6, 7);
      }
#pragma unroll
      for (int i = 0; i < 4; ++i)
#pragma unroll
        for (int j = 0; j < 4; ++j)
          acc[i][j] = __builtin_amdgcn_mfma_f32_16x16x32_bf16(af[i], bfr[j], acc[i][j], 0, 0, 0);
    }
    __syncthreads();
  }
}

#define ZERO_ACC4(acc)                                           \
  _Pragma("unroll") for (int i_ = 0; i_ < 4; ++i_)               \
  _Pragma("unroll") for (int j_ = 0; j_ < 4; ++j_)               \
      acc[i_][j_] = (float4v){0.f, 0.f, 0.f, 0.f};

// ============ 256x256 8-phase core, SINGLE barrier per phase ================
// (structure identical to round 10; see WAR/RAW audit there)
#define FRAG(tile, row, slog)                                                  \
  (*(const short8v*)((const char*)(tile) + (row) * 128 + ((((slog) ^ ((row) & 7))) * 16)))

#define LBAR()                                                                 \
  do { asm volatile("s_waitcnt lgkmcnt(0)" ::: "memory");                      \
       __builtin_amdgcn_s_barrier();                                           \
       __builtin_amdgcn_sched_barrier(0); asm volatile("" ::: "memory"); } while (0)

#define WAITVM6() asm volatile("s_waitcnt vmcnt(6)" ::: "memory")
#define WAITVM0() asm volatile("s_waitcnt vmcnt(0)" ::: "memory")

#define READA(Asrc, m0)                                                        \
  aF0  = FRAG(Asrc, wr * 128 + (m0) * 16 + l15, g);                            \
  aF0k = FRAG(Asrc, wr * 128 + (m0) * 16 + l15, 4 + g);                        \
  aF1  = FRAG(Asrc, wr * 128 + (m0) * 16 + 16 + l15, g);                       \
  aF1k = FRAG(Asrc, wr * 128 + (m0) * 16 + 16 + l15, 4 + g);

#define READB(Bsrc)                                                            \
  _Pragma("unroll") for (int j_ = 0; j_ < 4; ++j_) {                           \
    bF[0][j_] = FRAG(Bsrc, wc * 64 + j_ * 16 + l15, g);                        \
    bF[1][j_] = FRAG(Bsrc, wc * 64 + j_ * 16 + l15, 4 + g);                    \
  }

#define MFMA16(m0)                                                             \
  __builtin_amdgcn_s_setprio(1);                                               \
  _Pragma("unroll") for (int j_ = 0; j_ < 4; ++j_) {                           \
    acc[(m0)][j_]     = __builtin_amdgcn_mfma_f32_16x16x32_bf16(aF0,  bF[0][j_], acc[(m0)][j_], 0, 0, 0);     \
    acc[(m0) + 1][j_] = __builtin_amdgcn_mfma_f32_16x16x32_bf16(aF1,  bF[0][j_], acc[(m0) + 1][j_], 0, 0, 0); \
  }                                                                            \
  _Pragma("unroll") for (int j_ = 0; j_ < 4; ++j_) {                           \
    acc[(m0)][j_]     = __builtin_amdgcn_mfma_f32_16x16x32_bf16(aF0k, bF[1][j_], acc[(m0)][j_], 0, 0, 0);     \
    acc[(m0) + 1][j_] = __builtin_amdgcn_mfma_f32_16x16x32_bf16(aF1k, bF[1][j_], acc[(m0) + 1][j_], 0, 0, 0); \
  }                                                                            \
  __builtin_amdgcn_s_setprio(0);

#define STA(bufptr, c, t) GLOAD16((bufptr) + (c) * 4096 + ldsw, A + (size_t)(c) * 64 * 1024 + (t) * 64 + poff)
#define STB(bufptr, c, t) GLOAD16((bufptr) + (c) * 4096 + ldsw, B + (size_t)(c) * 64 * 1024 + (t) * 64 + poff)

__device__ __forceinline__ void gemm8_core(
    const u16* __restrict__ A, const u16* __restrict__ B,
    u16* As0, u16* As1, u16* Bs0, u16* Bs1, float4v acc[8][4]) {
  const int tid = threadIdx.x;
  const int lane = tid & 63, wid = tid >> 6;
  const int wr = wid >> 2, wc = wid & 3;
  const int l15 = lane & 15, g = lane >> 4;
  const int poff = (wid * 8 + (lane >> 3)) * 1024 + ((lane & 7) ^ ((lane >> 3) & 7)) * 8;
  const int ldsw = wid * 512;

  STB(Bs0, 0, 0); STB(Bs0, 1, 0); STB(Bs0, 2, 0); STB(Bs0, 3, 0);
  STA(As0, 0, 0); STA(As0, 1, 0); STA(As0, 2, 0); STA(As0, 3, 0);
  STB(Bs1, 0, 1); STB(Bs1, 1, 1); STB(Bs1, 2, 1); STB(Bs1, 3, 1);
  STA(As1, 0, 1); STA(As1, 2, 1);
  WAITVM6();
  __builtin_amdgcn_s_barrier();
  __builtin_amdgcn_sched_barrier(0);

  for (int i = 0; i < 8; ++i) {
    const int t1 = 2 * i + 1, t2 = 2 * i + 2, t3 = 2 * i + 3;
    const bool more = (i < 7);
    short8v bF[2][4];
    short8v aF0, aF0k, aF1, aF1k;
    // PH1
    READB(Bs0); READA(As0, 0);
    STA(As1, 1, t1); STA(As1, 3, t1);
    LBAR(); MFMA16(0);
    // PH2
    READA(As0, 2);
    if (more) { STB(Bs0, 0, t2); STB(Bs0, 1, t2); }
    LBAR(); MFMA16(2);
    // PH3
    READA(As0, 4);
    if (more) { STB(Bs0, 2, t2); STB(Bs0, 3, t2); }
    LBAR(); MFMA16(4);
    // PH4
    READA(As0, 6);
    if (more) { STA(As0, 0, t2); STA(As0, 2, t2); }
    if (more) { WAITVM6(); } else { WAITVM0(); }
    LBAR(); MFMA16(6);
    // PH5
    READB(Bs1); READA(As1, 0);
    if (more) { STA(As0, 1, t2); STA(As0, 3, t2); }
    LBAR(); MFMA16(0);
    // PH6
    READA(As1, 2);
    if (more) { STB(Bs1, 0, t3); STB(Bs1, 1, t3); }
    LBAR(); MFMA16(2);
    // PH7
    READA(As1, 4);
    if (more) { STB(Bs1, 2, t3); STB(Bs1, 3, t3); }
    LBAR(); MFMA16(4);
    // PH8
    READA(As1, 6);
    if (more) { STA(As1, 0, t3); STA(As1, 2, t3); }
    if (more) { WAITVM6(); }
    LBAR(); MFMA16(6);
  }
}

#define ZERO_ACC8(acc)                                           \
  _Pragma("unroll") for (int i_ = 0; i_ < 8; ++i_)               \
  _Pragma("unroll") for (int j_ = 0; j_ < 4; ++j_)               \
      acc[i_][j_] = (float4v){0.f, 0.f, 0.f, 0.f};

// ---------------------------------------------------------------------------
__global__ void __launch_bounds__(256) k_conv(const float* __restrict__ in,
                                              u16* __restrict__ out) {
  const int i = blockIdx.x * 256 + threadIdx.x;
  float4v v = __builtin_nontemporal_load(&((const float4v*)in)[i]);  // x read once
  const int row = i >> 8;
  const int c = (i & 255) * 4;
  ushort4v o;
  o[0] = f2bf(v[0]); o[1] = f2bf(v[1]); o[2] = f2bf(v[2]); o[3] = f2bf(v[3]);
  *(ushort4v*)(out + (size_t)row * 1024 + permp(c)) = o;
}

// ---------------------------------------------------------------------------
__global__ void __launch_bounds__(256) k_transpose(const float* __restrict__ in,
                                                   u16* __restrict__ out, int R, int C) {
  __shared__ u16 tile[64][65];
  const int nbc = C >> 6;
  const int bc = blockIdx.x % nbc, br = blockIdx.x / nbc;
  const int r0 = br * 64, c0 = bc * 64;
  const int t = threadIdx.x;
  const int lr = t >> 4;
  const int lc = (t & 15) * 4;
#pragma unroll
  for (int p = 0; p < 4; ++p) {
    const int r = p * 16 + lr;
    float4v v = *(const float4v*)(in + (size_t)(r0 + r) * C + c0 + lc);
    tile[r][lc + 0] = f2bf(v[0]); tile[r][lc + 1] = f2bf(v[1]);
    tile[r][lc + 2] = f2bf(v[2]); tile[r][lc + 3] = f2bf(v[3]);
  }
  __syncthreads();
#pragma unroll
  for (int p = 0; p < 4; ++p) {
    const int c = p * 16 + lr;
    ushort4v o;
    o[0] = tile[lc + 0][c]; o[1] = tile[lc + 1][c];
    o[2] = tile[lc + 2][c]; o[3] = tile[lc + 3][c];
    *(ushort4v*)(out + (size_t)(c0 + c) * R + permp(r0 + lc)) = o;
  }
}

// ---------------------------------------------------------------------------
// GEMM1 (8-phase, round-10 grid): h1 = x@W1 + b1 -> q / k_t / non_att
// non_att: bf16 -> nab (if ws fits) else fp32 NT -> dout.
// ---------------------------------------------------------------------------
__global__ void __launch_bounds__(512, 2) k_gemm1n(
    const u16* __restrict__ xb, const u16* __restrict__ w1t,
    const float* __restrict__ bias1, u16* __restrict__ qbuf,
    u16* __restrict__ ktb, u16* __restrict__ nab,
    float* __restrict__ dout, int use_nab) {
  __shared__ u16 As[2][16384], Bs[2][16384];
  const int wg = (blockIdx.x & 7) * 192 + (blockIdx.x >> 3);   // 1536 wgs
  const int mt = wg / 12, nt = wg % 12;                        // nt-fastest (A shared)
  float4v acc[8][4];
  ZERO_ACC8(acc);
  gemm8_core(xb + (size_t)mt * 256 * 1024, w1t + (size_t)nt * 256 * 1024,
             As[0], As[1], Bs[0], Bs[1], acc);
  const int lane = threadIdx.x & 63, wid = threadIdx.x >> 6;
  const int wr = wid >> 2, wc = wid & 3;
  const int l15 = lane & 15, g = lane >> 4;
  const int region = nt >> 2;
#pragma unroll
  for (int m = 0; m < 8; ++m) {
    const int rb = mt * 256 + wr * 128 + m * 16 + 4 * g;
#pragma unroll
    for (int j = 0; j < 4; ++j) {
      const int cg = nt * 256 + wc * 64 + j * 16 + l15;
      const float bia = bias1[cg];
      if (region == 0) {
#pragma unroll
        for (int r = 0; r < 4; ++r)
          qbuf[(size_t)(rb + r) * 1024 + cg] = f2bf(fmap(acc[m][j][r] + bia));
      } else if (region == 1) {
        const int rc = cg - 1024;
        ushort4v pk;
#pragma unroll
        for (int r = 0; r < 4; ++r) pk[r] = f2bf(fmap(acc[m][j][r] + bia));
        *(ushort4v*)(ktb + (size_t)rc * 32768 + rb) = pk;
      } else {
        const int rc = cg - 2048;
        if (use_nab) {
#pragma unroll
          for (int r = 0; r < 4; ++r)
            nab[(size_t)(rb + r) * 1024 + rc] = f2bf(acc[m][j][r] + bia);
        } else {
#pragma unroll
          for (int r = 0; r < 4; ++r)
            __builtin_nontemporal_store(acc[m][j][r] + bia,
                                        &dout[(size_t)(rb + r) * 1024 + rc]);
        }
      }
    }
  }
}

// ---------------------------------------------------------------------------
// GEMM2 (8-phase, round-10 grid): v = x@Wv + bv -> v_t [dim][N]
// ---------------------------------------------------------------------------
__global__ void __launch_bounds__(512, 2) k_gemm2n(
    const u16* __restrict__ xb, const u16* __restrict__ wvt,
    const float* __restrict__ biasv, u16* __restrict__ vtb) {
  __shared__ u16 As[2][16384], Bs[2][16384];
  const int wg = (blockIdx.x & 7) * 64 + (blockIdx.x >> 3);    // 512 wgs
  const int mt = wg >> 2, nt = wg & 3;                         // nt-fastest
  float4v acc[8][4];
  ZERO_ACC8(acc);
  gemm8_core(xb + (size_t)mt * 256 * 1024, wvt + (size_t)nt * 256 * 1024,
             As[0], As[1], Bs[0], Bs[1], acc);
  const int lane = threadIdx.x & 63, wid = threadIdx.x >> 6;
  const int wr = wid >> 2, wc = wid & 3;
  const int l15 = lane & 15, g = lane >> 4;
#pragma unroll
  for (int m = 0; m < 8; ++m) {
    const int rb = mt * 256 + wr * 128 + m * 16 + 4 * g;
#pragma unroll
    for (int j = 0; j < 4; ++j) {
      const int cg = nt * 256 + wc * 64 + j * 16 + l15;
      const float bia = biasv[cg];
      ushort4v pk;
#pragma unroll
      for (int r = 0; r < 4; ++r) pk[r] = f2bf(acc[m][j][r] + bia);
      *(ushort4v*)(vtb + (size_t)cg * 32768 + rb) = pk;
    }
  }
}

// ---------------------------------------------------------------------------
// kv partials (bf16) + fused k_sum partials. Per (head, K-chunk of 512):
// ---------------------------------------------------------------------------
__global__ void __launch_bounds__(256) k_kvpart(
    const u16* __restrict__ ktb, const u16* __restrict__ vtb,
    u16* __restrict__ part, float* __restrict__ kspart) {
  __shared__ u16 Al[128 * 64], Bl[128 * 64];
  const int h = blockIdx.x >> 6, ch = blockIdx.x & 63;
  float4v acc[4][4];
  ZERO_ACC4(acc);
  gemm_core(ktb + (size_t)h * 128 * 32768, 32768,
            vtb + (size_t)h * 128 * 32768, 32768, 0, 0, ch * 512, 8, Al, Bl, acc);
  u16* o = part + (size_t)(h * 64 + ch) * 16384;
  const int lane = threadIdx.x & 63, wid = threadIdx.x >> 6;
  const int wr = wid >> 1, wc = wid & 1;
#pragma unroll
  for (int i = 0; i < 4; ++i) {
    const int rb = wr * 64 + i * 16 + 4 * (lane >> 4);
#pragma unroll
    for (int j = 0; j < 4; ++j) {
      const int cg = wc * 64 + j * 16 + (lane & 15);
#pragma unroll
      for (int r = 0; r < 4; ++r) o[(size_t)(rb + r) * 128 + cg] = f2bf(acc[i][j][r]);
    }
  }
  // fused k_sum partial: rows are L2/L3-hot (just staged above).
  float* ksp = kspart + (size_t)(h * 64 + ch) * 128;
#pragma unroll
  for (int it = 0; it < 8; ++it) {
    const int row = it * 16 + wid * 4 + (lane >> 4);
    const u16* src = ktb + (size_t)(h * 128 + row) * 32768 + ch * 512 + (lane & 15) * 32;
    float s = 0.f;
#pragma unroll
    for (int u = 0; u < 4; ++u) {
      short8v v = *(const short8v*)(src + u * 8);
#pragma unroll
      for (int e = 0; e < 8; ++e) s += bf2f((u16)v[e]);
    }
#pragma unroll
    for (int m = 1; m < 16; m <<= 1) s += __shfl_xor(s, m, 64);
    if ((lane & 15) == 0) ksp[row] = s;
  }
}

// ---------------------------------------------------------------------------
__global__ void __launch_bounds__(128) k_kvred(const u16* __restrict__ part,
                                               const float* __restrict__ kspart,
                                               u16* __restrict__ kvt,
                                               float* __restrict__ ksum) {
  const int b = blockIdx.x;
  const int h = b >> 7, kd = b & 127;
  const int vd = threadIdx.x;
  const u16* p = part + (size_t)h * 64 * 16384 + (size_t)kd * 128 + vd;
  float s = 0.f;
#pragma unroll
  for (int c = 0; c < 64; ++c) s += bf2f(p[(size_t)c * 16384]);
  kvt[(size_t)(h * 128 + vd) * 128 + kd] = f2bf(s);
  __shared__ float red[64];
  if (vd < 64) red[vd] = kspart[(size_t)(h * 64 + vd) * 128 + kd];
  __syncthreads();
  if (vd < 32) red[vd] += red[vd + 32];
  __syncthreads();
  if (vd == 0) {
    float t = 0.f;
#pragma unroll
    for (int c = 0; c < 32; ++c) t += red[c];
    ksum[h * 128 + kd] = t;
  }
}

// ---------------------------------------------------------------------------
// att = (q @ kv) / (q . k_sum); writes att k-PERMUTED (consumed by gemmo)
// ---------------------------------------------------------------------------
__global__ void __launch_bounds__(256) k_attn(
    const u16* __restrict__ q, const u16* __restrict__ kvt,
    const float* __restrict__ ksum, u16* __restrict__ att) {
  __shared__ u16 qlds[128 * 128];
  __shared__ u16 blds[128 * 128];
  __shared__ float ksl[128];
  __shared__ float qkl[128];
  const int b = blockIdx.x;
  const int h = b >> 8, nt = b & 255;
  const int n0 = nt * 128;
  const int tid = threadIdx.x, lane = tid & 63, wid = tid >> 6;
  const int wr = wid >> 1, wc = wid & 1;
  const int sr = lane >> 4;
#pragma unroll
  for (int jj = 0; jj < 8; ++jj) {
    const int rb = wid * 32 + jj * 4;
    const int srcslot = (lane & 15) ^ ((rb + (lane >> 4)) & 15);
    GLOAD16(qlds + rb * 128, q + (size_t)(n0 + rb + sr) * 1024 + h * 128 + srcslot * 8);
    GLOAD16(blds + rb * 128, kvt + (size_t)(h * 128 + rb + sr) * 128 + srcslot * 8);
  }
  if (tid < 128) ksl[tid] = ksum[h * 128 + tid];
  __syncthreads();
  if (tid < 128) {
    float s = 0.f;
    const int rsw = tid & 15;
#pragma unroll
    for (int ii = 0; ii < 16; ++ii) {
      const int slot = ii ^ rsw;
      short8v v = *(const short8v*)((const char*)qlds + tid * 256 + slot * 16);
#pragma unroll
      for (int e = 0; e < 8; ++e) s += bf2f((u16)v[e]) * ksl[ii * 8 + e];
    }
    qkl[tid] = (s == 0.f) ? 1e-5f : s;
  }
  float4v acc[4][4];
  ZERO_ACC4(acc);
  const int swz = (lane & 15) << 4;
  const int g4 = 4 * (lane >> 4);
#pragma unroll
  for (int kk = 0; kk < 128; kk += 32) {
    const int c0 = 2 * (kk + g4);
    short8v af[4], bfr[4];
#pragma unroll
    for (int i = 0; i < 4; ++i) {
      const char* pa = (const char*)(qlds + (wr * 64 + i * 16 + (lane & 15)) * 128);
      short4v a0 = *(const short4v*)(pa + (c0 ^ swz));
      short4v a1 = *(const short4v*)(pa + ((c0 + 32) ^ swz));
      af[i] = __builtin_shufflevector(a0, a1, 0, 1, 2, 3, 4, 5, 6, 7);
      const char* pb = (const char*)(blds + (wc * 64 + i * 16 + (lane & 15)) * 128);
      short4v b0 = *(const short4v*)(pb + (c0 ^ swz));
      short4v b1 = *(const short4v*)(pb + ((c0 + 32) ^ swz));
      bfr[i] = __builtin_shufflevector(b0, b1, 0, 1, 2, 3, 4, 5, 6, 7);
    }
#pragma unroll
    for (int i = 0; i < 4; ++i)
#pragma unroll
      for (int j = 0; j < 4; ++j)
        acc[i][j] = __builtin_amdgcn_mfma_f32_16x16x32_bf16(af[i], bfr[j], acc[i][j], 0, 0, 0);
  }
  __syncthreads();
#pragma unroll
  for (int i = 0; i < 4; ++i) {
    const int rl = wr * 64 + i * 16 + 4 * (lane >> 4);
#pragma unroll
    for (int j = 0; j < 4; ++j) {
      const int cl = wc * 64 + j * 16 + (lane & 15);
      const int pc = permp(h * 128 + cl);
#pragma unroll
      for (int r = 0; r < 4; ++r) {
        const float v = acc[i][j][r] / qkl[rl + r];
        att[(size_t)(n0 + rl + r) * 1024 + pc] = f2bf(v);
      }
    }
  }
}

// ---------------------------------------------------------------------------
// GEMMo (8-phase, round-10 grid): out = non_att + att@Wo + bo (NT final store)
// non_att from nab (bf16) if use_nab else RMW dout.
// ---------------------------------------------------------------------------
__global__ void __launch_bounds__(512, 2) k_gemmon(
    const u16* __restrict__ attb, const u16* __restrict__ wot,
    const float* __restrict__ biaso, const u16* __restrict__ nab,
    float* __restrict__ dout, int use_nab) {
  __shared__ u16 As[2][16384], Bs[2][16384];
  const int wg = (blockIdx.x & 7) * 64 + (blockIdx.x >> 3);    // 512 wgs
  const int mt = wg >> 2, nt = wg & 3;                         // nt-fastest
  float4v acc[8][4];
  ZERO_ACC8(acc);
  gemm8_core(attb + (size_t)mt * 256 * 1024, wot + (size_t)nt * 256 * 1024,
             As[0], As[1], Bs[0], Bs[1], acc);
  const int lane = threadIdx.x & 63, wid = threadIdx.x >> 6;
  const int wr = wid >> 2, wc = wid & 3;
  const int l15 = lane & 15, g = lane >> 4;
#pragma unroll
  for (int m = 0; m < 8; ++m) {
    const int rb = mt * 256 + wr * 128 + m * 16 + 4 * g;
#pragma unroll
    for (int j = 0; j < 4; ++j) {
      const int cg = nt * 256 + wc * 64 + j * 16 + l15;
      const float bia = biaso[cg];
      if (use_nab) {
#pragma unroll
        for (int r = 0; r < 4; ++r) {
          const size_t idx = (size_t)(rb + r) * 1024 + cg;
          const float v = bf2f(nab[idx]) + acc[m][j][r] + bia;
          __builtin_nontemporal_store(v, &dout[idx]);
        }
      } else {
#pragma unroll
        for (int r = 0; r < 4; ++r) {
          const size_t idx = (size_t)(rb + r) * 1024 + cg;
          const float v = dout[idx] + acc[m][j][r] + bia;
          __builtin_nontemporal_store(v, &dout[idx]);
        }
      }
    }
  }
}

// ---------------------------------------------------------------------------
extern "C" void kernel_launch(void* const* d_in, const int* in_sizes, int n_in,
                              void* d_out, int out_size, void* d_ws, size_t ws_size,
                              hipStream_t stream) {
  const float* x  = (const float*)d_in[0];
  const float* W1 = (const float*)d_in[1];
  const float* b1 = (const float*)d_in[2];
  const float* Wv = (const float*)d_in[3];
  const float* bv = (const float*)d_in[4];
  const float* Wo = (const float*)d_in[5];
  const float* bo = (const float*)d_in[6];
  float* out = (float*)d_out;

  const size_t N = 32768;
  u16* xb   = (u16*)d_ws;                       // x bf16 perm-k [N][1024]
  u16* qb   = xb  + N * 1024;                   // q (then att, perm-k)
  u16* ktb  = qb  + N * 1024;                   // k_t [8*128][N]
  u16* vtb  = ktb + N * 1024;                   // v_t [8*128][N]
  u16* wcat = vtb + N * 1024;                   // [W1|Wv]^T perm-k [4096][1024]
  u16* wot  = wcat + (size_t)4096 * 1024;       // Wo^T perm-k
  u16* part = wot + (size_t)1024 * 1024;        // kv partials bf16 [8][64][16384]
  u16* kvt  = part + (size_t)8 * 64 * 16384;    // kv_t [h][vd][kd]
  float* ksum = (float*)(kvt + (size_t)8 * 16384);    // [8][128]
  float* kspart = ksum + 1024;                        // [8][64][128]
  u16* nab  = (u16*)(kspart + (size_t)8 * 64 * 128);  // non_att bf16 (optional)
  const size_t need_nab = (size_t)((const char*)(nab + N * 1024) - (const char*)d_ws);
  const int use_nab = ws_size >= need_nab ? 1 : 0;

  k_conv<<<32768, 256, 0, stream>>>(x, xb);
  k_transpose<<<768, 256, 0, stream>>>(W1, wcat, 1024, 3072);
  k_transpose<<<256, 256, 0, stream>>>(Wv, wcat + (size_t)3072 * 1024, 1024, 1024);
  k_transpose<<<256, 256, 0, stream>>>(Wo, wot, 1024, 1024);
  k_gemm1n<<<1536, 512, 0, stream>>>(xb, wcat, b1, qb, ktb, nab, out, use_nab);
  k_gemm2n<<<512, 512, 0, stream>>>(xb, wcat + (size_t)3072 * 1024, bv, vtb);
  k_kvpart<<<512, 256, 0, stream>>>(ktb, vtb, part, kspart);
  k_kvred<<<1024, 128, 0, stream>>>(part, kspart, kvt, ksum);
  k_attn<<<2048, 256, 0, stream>>>(qb, kvt, ksum, qb);
  k_gemmon<<<512, 512, 0, stream>>>(qb, wot, bo, nab, out, use_nab);
}

// Round 13
// 547.306 us; speedup vs baseline: 1.2411x; 1.0306x over previous
//
#include <hip/hip_runtime.h>

typedef unsigned short u16;
typedef __attribute__((ext_vector_type(4))) short short4v;
typedef __attribute__((ext_vector_type(8))) short short8v;
typedef __attribute__((ext_vector_type(4))) unsigned short ushort4v;
typedef __attribute__((ext_vector_type(4))) float float4v;

#define GLOAD16(ldsp, gp)                                                      \
  __builtin_amdgcn_global_load_lds(                                            \
      (const __attribute__((address_space(1))) unsigned int*)(gp),             \
      (__attribute__((address_space(3))) unsigned int*)(ldsp), 16, 0, 0)

__device__ __forceinline__ u16 f2bf(float f) {
  union { float f; unsigned u; } v; v.f = f;
  unsigned r = v.u + 0x7fffu + ((v.u >> 16) & 1u);
  return (u16)(r >> 16);
}
__device__ __forceinline__ float bf2f(u16 h) {
  union { unsigned u; float f; } v; v.u = ((unsigned)h) << 16;
  return v.f;
}
__device__ __forceinline__ float fmap(float x) { return x > 0.f ? x + 1.f : __expf(x); }

// k-permutation: storage position 8g+j (within a 32-block) holds k = 4g + (j<4? j : 12+j).
__device__ __forceinline__ int permp(int k) {
  const int r5 = k & 31;
  const int p = (r5 < 16) ? ((r5 >> 2) * 8 + (r5 & 3))
                          : (((r5 - 16) >> 2) * 8 + 4 + ((r5 - 16) & 3));
  return (k & ~31) + p;
}

#define ZERO_ACC4(acc)                                           \
  _Pragma("unroll") for (int i_ = 0; i_ < 4; ++i_)               \
  _Pragma("unroll") for (int j_ = 0; j_ < 4; ++j_)               \
      acc[i_][j_] = (float4v){0.f, 0.f, 0.f, 0.f};

// ============ 256x256 8-phase core, SINGLE barrier per phase ================
// (structure identical to round 10; see WAR/RAW audit there)
#define FRAG(tile, row, slog)                                                  \
  (*(const short8v*)((const char*)(tile) + (row) * 128 + ((((slog) ^ ((row) & 7))) * 16)))

#define LBAR()                                                                 \
  do { asm volatile("s_waitcnt lgkmcnt(0)" ::: "memory");                      \
       __builtin_amdgcn_s_barrier();                                           \
       __builtin_amdgcn_sched_barrier(0); asm volatile("" ::: "memory"); } while (0)

#define WAITVM6() asm volatile("s_waitcnt vmcnt(6)" ::: "memory")
#define WAITVM0() asm volatile("s_waitcnt vmcnt(0)" ::: "memory")

#define READA(Asrc, m0)                                                        \
  aF0  = FRAG(Asrc, wr * 128 + (m0) * 16 + l15, g);                            \
  aF0k = FRAG(Asrc, wr * 128 + (m0) * 16 + l15, 4 + g);                        \
  aF1  = FRAG(Asrc, wr * 128 + (m0) * 16 + 16 + l15, g);                       \
  aF1k = FRAG(Asrc, wr * 128 + (m0) * 16 + 16 + l15, 4 + g);

#define READB(Bsrc)                                                            \
  _Pragma("unroll") for (int j_ = 0; j_ < 4; ++j_) {                           \
    bF[0][j_] = FRAG(Bsrc, wc * 64 + j_ * 16 + l15, g);                        \
    bF[1][j_] = FRAG(Bsrc, wc * 64 + j_ * 16 + l15, 4 + g);                    \
  }

#define MFMA16(m0)                                                             \
  __builtin_amdgcn_s_setprio(1);                                               \
  _Pragma("unroll") for (int j_ = 0; j_ < 4; ++j_) {                           \
    acc[(m0)][j_]     = __builtin_amdgcn_mfma_f32_16x16x32_bf16(aF0,  bF[0][j_], acc[(m0)][j_], 0, 0, 0);     \
    acc[(m0) + 1][j_] = __builtin_amdgcn_mfma_f32_16x16x32_bf16(aF1,  bF[0][j_], acc[(m0) + 1][j_], 0, 0, 0); \
  }                                                                            \
  _Pragma("unroll") for (int j_ = 0; j_ < 4; ++j_) {                           \
    acc[(m0)][j_]     = __builtin_amdgcn_mfma_f32_16x16x32_bf16(aF0k, bF[1][j_], acc[(m0)][j_], 0, 0, 0);     \
    acc[(m0) + 1][j_] = __builtin_amdgcn_mfma_f32_16x16x32_bf16(aF1k, bF[1][j_], acc[(m0) + 1][j_], 0, 0, 0); \
  }                                                                            \
  __builtin_amdgcn_s_setprio(0);

#define STA(bufptr, c, t) GLOAD16((bufptr) + (c) * 4096 + ldsw, A + (size_t)(c) * 64 * 1024 + (t) * 64 + poff)
#define STB(bufptr, c, t) GLOAD16((bufptr) + (c) * 4096 + ldsw, B + (size_t)(c) * 64 * 1024 + (t) * 64 + poff)

__device__ __forceinline__ void gemm8_core(
    const u16* __restrict__ A, const u16* __restrict__ B,
    u16* As0, u16* As1, u16* Bs0, u16* Bs1, float4v acc[8][4]) {
  const int tid = threadIdx.x;
  const int lane = tid & 63, wid = tid >> 6;
  const int wr = wid >> 2, wc = wid & 3;
  const int l15 = lane & 15, g = lane >> 4;
  const int poff = (wid * 8 + (lane >> 3)) * 1024 + ((lane & 7) ^ ((lane >> 3) & 7)) * 8;
  const int ldsw = wid * 512;

  STB(Bs0, 0, 0); STB(Bs0, 1, 0); STB(Bs0, 2, 0); STB(Bs0, 3, 0);
  STA(As0, 0, 0); STA(As0, 1, 0); STA(As0, 2, 0); STA(As0, 3, 0);
  STB(Bs1, 0, 1); STB(Bs1, 1, 1); STB(Bs1, 2, 1); STB(Bs1, 3, 1);
  STA(As1, 0, 1); STA(As1, 2, 1);
  WAITVM6();
  __builtin_amdgcn_s_barrier();
  __builtin_amdgcn_sched_barrier(0);

  for (int i = 0; i < 8; ++i) {
    const int t1 = 2 * i + 1, t2 = 2 * i + 2, t3 = 2 * i + 3;
    const bool more = (i < 7);
    short8v bF[2][4];
    short8v aF0, aF0k, aF1, aF1k;
    // PH1
    READB(Bs0); READA(As0, 0);
    STA(As1, 1, t1); STA(As1, 3, t1);
    LBAR(); MFMA16(0);
    // PH2
    READA(As0, 2);
    if (more) { STB(Bs0, 0, t2); STB(Bs0, 1, t2); }
    LBAR(); MFMA16(2);
    // PH3
    READA(As0, 4);
    if (more) { STB(Bs0, 2, t2); STB(Bs0, 3, t2); }
    LBAR(); MFMA16(4);
    // PH4
    READA(As0, 6);
    if (more) { STA(As0, 0, t2); STA(As0, 2, t2); }
    if (more) { WAITVM6(); } else { WAITVM0(); }
    LBAR(); MFMA16(6);
    // PH5
    READB(Bs1); READA(As1, 0);
    if (more) { STA(As0, 1, t2); STA(As0, 3, t2); }
    LBAR(); MFMA16(0);
    // PH6
    READA(As1, 2);
    if (more) { STB(Bs1, 0, t3); STB(Bs1, 1, t3); }
    LBAR(); MFMA16(2);
    // PH7
    READA(As1, 4);
    if (more) { STB(Bs1, 2, t3); STB(Bs1, 3, t3); }
    LBAR(); MFMA16(4);
    // PH8
    READA(As1, 6);
    if (more) { STA(As1, 0, t3); STA(As1, 2, t3); }
    if (more) { WAITVM6(); }
    LBAR(); MFMA16(6);
  }
}

#define ZERO_ACC8(acc)                                           \
  _Pragma("unroll") for (int i_ = 0; i_ < 8; ++i_)               \
  _Pragma("unroll") for (int j_ = 0; j_ < 4; ++j_)               \
      acc[i_][j_] = (float4v){0.f, 0.f, 0.f, 0.f};

// ---------------------------------------------------------------------------
__global__ void __launch_bounds__(256) k_conv(const float* __restrict__ in,
                                              u16* __restrict__ out) {
  const int base = blockIdx.x * 1024 + threadIdx.x;   // 8192 blocks, 4 float4/thread
#pragma unroll
  for (int u = 0; u < 4; ++u) {
    const int i = base + u * 256;
    float4v v = __builtin_nontemporal_load(&((const float4v*)in)[i]);
    const int row = i >> 8;
    const int c = (i & 255) * 4;
    ushort4v o;
    o[0] = f2bf(v[0]); o[1] = f2bf(v[1]); o[2] = f2bf(v[2]); o[3] = f2bf(v[3]);
    *(ushort4v*)(out + (size_t)row * 1024 + permp(c)) = o;
  }
}

// ---------------------------------------------------------------------------
__global__ void __launch_bounds__(256) k_transpose(const float* __restrict__ in,
                                                   u16* __restrict__ out, int R, int C) {
  __shared__ u16 tile[64][65];
  const int nbc = C >> 6;
  const int bc = blockIdx.x % nbc, br = blockIdx.x / nbc;
  const int r0 = br * 64, c0 = bc * 64;
  const int t = threadIdx.x;
  const int lr = t >> 4;
  const int lc = (t & 15) * 4;
#pragma unroll
  for (int p = 0; p < 4; ++p) {
    const int r = p * 16 + lr;
    float4v v = *(const float4v*)(in + (size_t)(r0 + r) * C + c0 + lc);
    tile[r][lc + 0] = f2bf(v[0]); tile[r][lc + 1] = f2bf(v[1]);
    tile[r][lc + 2] = f2bf(v[2]); tile[r][lc + 3] = f2bf(v[3]);
  }
  __syncthreads();
#pragma unroll
  for (int p = 0; p < 4; ++p) {
    const int c = p * 16 + lr;
    ushort4v o;
    o[0] = tile[lc + 0][c]; o[1] = tile[lc + 1][c];
    o[2] = tile[lc + 2][c]; o[3] = tile[lc + 3][c];
    *(ushort4v*)(out + (size_t)(c0 + c) * R + permp(r0 + lc)) = o;
  }
}

// ---------------------------------------------------------------------------
// GEMM1 (8-phase, round-10 grid): h1 = x@W1 + b1 -> q / k_t / non_att
// non_att: bf16 -> nab (if ws fits) else fp32 NT -> dout.
// ---------------------------------------------------------------------------
__global__ void __launch_bounds__(512, 2) k_gemm1n(
    const u16* __restrict__ xb, const u16* __restrict__ w1t,
    const float* __restrict__ bias1, u16* __restrict__ qbuf,
    u16* __restrict__ ktb, u16* __restrict__ nab,
    float* __restrict__ dout, int use_nab) {
  __shared__ u16 As[2][16384], Bs[2][16384];
  const int wg = (blockIdx.x & 7) * 192 + (blockIdx.x >> 3);   // 1536 wgs
  const int mt = wg / 12, nt = wg % 12;                        // nt-fastest (A shared)
  float4v acc[8][4];
  ZERO_ACC8(acc);
  gemm8_core(xb + (size_t)mt * 256 * 1024, w1t + (size_t)nt * 256 * 1024,
             As[0], As[1], Bs[0], Bs[1], acc);
  const int lane = threadIdx.x & 63, wid = threadIdx.x >> 6;
  const int wr = wid >> 2, wc = wid & 3;
  const int l15 = lane & 15, g = lane >> 4;
  const int region = nt >> 2;
#pragma unroll
  for (int m = 0; m < 8; ++m) {
    const int rb = mt * 256 + wr * 128 + m * 16 + 4 * g;
#pragma unroll
    for (int j = 0; j < 4; ++j) {
      const int cg = nt * 256 + wc * 64 + j * 16 + l15;
      const float bia = bias1[cg];
      if (region == 0) {
#pragma unroll
        for (int r = 0; r < 4; ++r)
          qbuf[(size_t)(rb + r) * 1024 + cg] = f2bf(fmap(acc[m][j][r] + bia));
      } else if (region == 1) {
        const int rc = cg - 1024;
        ushort4v pk;
#pragma unroll
        for (int r = 0; r < 4; ++r) pk[r] = f2bf(fmap(acc[m][j][r] + bia));
        *(ushort4v*)(ktb + (size_t)rc * 32768 + rb) = pk;
      } else {
        const int rc = cg - 2048;
        if (use_nab) {
#pragma unroll
          for (int r = 0; r < 4; ++r)
            nab[(size_t)(rb + r) * 1024 + rc] = f2bf(acc[m][j][r] + bia);
        } else {
#pragma unroll
          for (int r = 0; r < 4; ++r)
            __builtin_nontemporal_store(acc[m][j][r] + bia,
                                        &dout[(size_t)(rb + r) * 1024 + rc]);
        }
      }
    }
  }
}

// ---------------------------------------------------------------------------
// GEMM2 (8-phase, round-10 grid): v = x@Wv + bv -> v_t [dim][N]
// ---------------------------------------------------------------------------
__global__ void __launch_bounds__(512, 2) k_gemm2n(
    const u16* __restrict__ xb, const u16* __restrict__ wvt,
    const float* __restrict__ biasv, u16* __restrict__ vtb) {
  __shared__ u16 As[2][16384], Bs[2][16384];
  const int wg = (blockIdx.x & 7) * 64 + (blockIdx.x >> 3);    // 512 wgs
  const int mt = wg >> 2, nt = wg & 3;                         // nt-fastest
  float4v acc[8][4];
  ZERO_ACC8(acc);
  gemm8_core(xb + (size_t)mt * 256 * 1024, wvt + (size_t)nt * 256 * 1024,
             As[0], As[1], Bs[0], Bs[1], acc);
  const int lane = threadIdx.x & 63, wid = threadIdx.x >> 6;
  const int wr = wid >> 2, wc = wid & 3;
  const int l15 = lane & 15, g = lane >> 4;
#pragma unroll
  for (int m = 0; m < 8; ++m) {
    const int rb = mt * 256 + wr * 128 + m * 16 + 4 * g;
#pragma unroll
    for (int j = 0; j < 4; ++j) {
      const int cg = nt * 256 + wc * 64 + j * 16 + l15;
      const float bia = biasv[cg];
      ushort4v pk;
#pragma unroll
      for (int r = 0; r < 4; ++r) pk[r] = f2bf(acc[m][j][r] + bia);
      *(ushort4v*)(vtb + (size_t)cg * 32768 + rb) = pk;
    }
  }
}

// ---------------------------------------------------------------------------
// kv partials (bf16) + k_sum partials computed FROM THE STAGED LDS TILES
// (full-row sum is swizzle-invariant; no global re-read of ktb).
// Per (head, K-chunk of 512): 128x128 GEMM over 8 staged K-steps.
// ---------------------------------------------------------------------------
__global__ void __launch_bounds__(256) k_kvpart(
    const u16* __restrict__ ktb, const u16* __restrict__ vtb,
    u16* __restrict__ part, float* __restrict__ kspart) {
  __shared__ u16 Al[128 * 64], Bl[128 * 64];
  const int h = blockIdx.x >> 6, ch = blockIdx.x & 63;
  const u16* A = ktb + (size_t)h * 128 * 32768;
  const u16* B = vtb + (size_t)h * 128 * 32768;
  const int k0 = ch * 512;
  const int lane = threadIdx.x & 63;
  const int wid  = threadIdx.x >> 6;
  const int wr = wid >> 1, wc = wid & 1;
  const int sr = lane >> 3;
  const int sc = ((lane & 7) ^ (lane >> 3)) * 8;
  const int swz = (lane & 7) << 4;
  const int g4 = 4 * (lane >> 4);
  float4v acc[4][4];
  ZERO_ACC4(acc);
  // k-sum state: lane l sums row (32*wid + (l>>1)), column-half (l&1)
  const int krow = wid * 32 + (lane >> 1);
  const int khalf = lane & 1;
  float ks = 0.f;
  for (int kt = 0; kt < 8; ++kt) {
    const int kb = k0 + kt * 64;
#pragma unroll
    for (int jj = 0; jj < 4; ++jj) {
      const int rb = wid * 8 + jj * 32;
      GLOAD16(Al + rb * 64, A + (size_t)(rb + sr) * 32768 + kb + sc);
      GLOAD16(Bl + rb * 64, B + (size_t)(rb + sr) * 32768 + kb + sc);
    }
    __syncthreads();
#pragma unroll
    for (int kk = 0; kk < 64; kk += 32) {
      const int c0 = 2 * (kk + g4);
      short8v af[4], bfr[4];
#pragma unroll
      for (int i = 0; i < 4; ++i) {
        const char* pa = (const char*)(Al + (wr * 64 + i * 16 + (lane & 15)) * 64);
        short4v a0 = *(const short4v*)(pa + (c0 ^ swz));
        short4v a1 = *(const short4v*)(pa + ((c0 + 32) ^ swz));
        af[i] = __builtin_shufflevector(a0, a1, 0, 1, 2, 3, 4, 5, 6, 7);
        const char* pb = (const char*)(Bl + (wc * 64 + i * 16 + (lane & 15)) * 64);
        short4v b0 = *(const short4v*)(pb + (c0 ^ swz));
        short4v b1 = *(const short4v*)(pb + ((c0 + 32) ^ swz));
        bfr[i] = __builtin_shufflevector(b0, b1, 0, 1, 2, 3, 4, 5, 6, 7);
      }
#pragma unroll
      for (int i = 0; i < 4; ++i)
#pragma unroll
        for (int j = 0; j < 4; ++j)
          acc[i][j] = __builtin_amdgcn_mfma_f32_16x16x32_bf16(af[i], bfr[j], acc[i][j], 0, 0, 0);
    }
    // k-sum from staged Al (valid until trailing barrier); rotated slot order
    // spreads bank groups (~4-way worst case).
#pragma unroll
    for (int i = 0; i < 4; ++i) {
      const int slot = (i + (lane >> 1)) & 3;
      short8v v = *(const short8v*)(Al + krow * 64 + khalf * 32 + slot * 8);
#pragma unroll
      for (int e = 0; e < 8; ++e) ks += bf2f((u16)v[e]);
    }
    __syncthreads();
  }
  u16* o = part + (size_t)(h * 64 + ch) * 16384;
#pragma unroll
  for (int i = 0; i < 4; ++i) {
    const int rb = wr * 64 + i * 16 + 4 * (lane >> 4);
#pragma unroll
    for (int j = 0; j < 4; ++j) {
      const int cg = wc * 64 + j * 16 + (lane & 15);
#pragma unroll
      for (int r = 0; r < 4; ++r) o[(size_t)(rb + r) * 128 + cg] = f2bf(acc[i][j][r]);
    }
  }
  ks += __shfl_xor(ks, 1, 64);
  if ((lane & 1) == 0)
    kspart[(size_t)(h * 64 + ch) * 128 + krow] = ks;
}

// ---------------------------------------------------------------------------
__global__ void __launch_bounds__(128) k_kvred(const u16* __restrict__ part,
                                               const float* __restrict__ kspart,
                                               u16* __restrict__ kvt,
                                               float* __restrict__ ksum) {
  const int b = blockIdx.x;
  const int h = b >> 7, kd = b & 127;
  const int vd = threadIdx.x;
  const u16* p = part + (size_t)h * 64 * 16384 + (size_t)kd * 128 + vd;
  float s = 0.f;
#pragma unroll
  for (int c = 0; c < 64; ++c) s += bf2f(__builtin_nontemporal_load(&p[(size_t)c * 16384]));
  kvt[(size_t)(h * 128 + vd) * 128 + kd] = f2bf(s);
  __shared__ float red[64];
  if (vd < 64) red[vd] = kspart[(size_t)(h * 64 + vd) * 128 + kd];
  __syncthreads();
  if (vd < 32) red[vd] += red[vd + 32];
  __syncthreads();
  if (vd == 0) {
    float t = 0.f;
#pragma unroll
    for (int c = 0; c < 32; ++c) t += red[c];
    ksum[h * 128 + kd] = t;
  }
}

// ---------------------------------------------------------------------------
// att = (q @ kv) / (q . k_sum); writes att k-PERMUTED (consumed by gemmo)
// ---------------------------------------------------------------------------
__global__ void __launch_bounds__(256) k_attn(
    const u16* __restrict__ q, const u16* __restrict__ kvt,
    const float* __restrict__ ksum, u16* __restrict__ att) {
  __shared__ u16 qlds[128 * 128];
  __shared__ u16 blds[128 * 128];
  __shared__ float ksl[128];
  __shared__ float qkl[128];
  const int b = blockIdx.x;
  const int h = b >> 8, nt = b & 255;
  const int n0 = nt * 128;
  const int tid = threadIdx.x, lane = tid & 63, wid = tid >> 6;
  const int wr = wid >> 1, wc = wid & 1;
  const int sr = lane >> 4;
#pragma unroll
  for (int jj = 0; jj < 8; ++jj) {
    const int rb = wid * 32 + jj * 4;
    const int srcslot = (lane & 15) ^ ((rb + (lane >> 4)) & 15);
    GLOAD16(qlds + rb * 128, q + (size_t)(n0 + rb + sr) * 1024 + h * 128 + srcslot * 8);
    GLOAD16(blds + rb * 128, kvt + (size_t)(h * 128 + rb + sr) * 128 + srcslot * 8);
  }
  if (tid < 128) ksl[tid] = ksum[h * 128 + tid];
  __syncthreads();
  if (tid < 128) {
    float s = 0.f;
    const int rsw = tid & 15;
#pragma unroll
    for (int ii = 0; ii < 16; ++ii) {
      const int slot = ii ^ rsw;
      short8v v = *(const short8v*)((const char*)qlds + tid * 256 + slot * 16);
#pragma unroll
      for (int e = 0; e < 8; ++e) s += bf2f((u16)v[e]) * ksl[ii * 8 + e];
    }
    qkl[tid] = (s == 0.f) ? 1e-5f : s;
  }
  float4v acc[4][4];
  ZERO_ACC4(acc);
  const int swz = (lane & 15) << 4;
  const int g4 = 4 * (lane >> 4);
#pragma unroll
  for (int kk = 0; kk < 128; kk += 32) {
    const int c0 = 2 * (kk + g4);
    short8v af[4], bfr[4];
#pragma unroll
    for (int i = 0; i < 4; ++i) {
      const char* pa = (const char*)(qlds + (wr * 64 + i * 16 + (lane & 15)) * 128);
      short4v a0 = *(const short4v*)(pa + (c0 ^ swz));
      short4v a1 = *(const short4v*)(pa + ((c0 + 32) ^ swz));
      af[i] = __builtin_shufflevector(a0, a1, 0, 1, 2, 3, 4, 5, 6, 7);
      const char* pb = (const char*)(blds + (wc * 64 + i * 16 + (lane & 15)) * 128);
      short4v b0 = *(const short4v*)(pb + (c0 ^ swz));
      short4v b1 = *(const short4v*)(pb + ((c0 + 32) ^ swz));
      bfr[i] = __builtin_shufflevector(b0, b1, 0, 1, 2, 3, 4, 5, 6, 7);
    }
#pragma unroll
    for (int i = 0; i < 4; ++i)
#pragma unroll
      for (int j = 0; j < 4; ++j)
        acc[i][j] = __builtin_amdgcn_mfma_f32_16x16x32_bf16(af[i], bfr[j], acc[i][j], 0, 0, 0);
  }
  __syncthreads();
#pragma unroll
  for (int i = 0; i < 4; ++i) {
    const int rl = wr * 64 + i * 16 + 4 * (lane >> 4);
#pragma unroll
    for (int j = 0; j < 4; ++j) {
      const int cl = wc * 64 + j * 16 + (lane & 15);
      const int pc = permp(h * 128 + cl);
#pragma unroll
      for (int r = 0; r < 4; ++r) {
        const float v = acc[i][j][r] / qkl[rl + r];
        att[(size_t)(n0 + rl + r) * 1024 + pc] = f2bf(v);
      }
    }
  }
}

// ---------------------------------------------------------------------------
// GEMMo (8-phase, round-10 grid): out = non_att + att@Wo + bo (NT final store)
// non_att from nab (bf16) if use_nab else RMW dout.
// ---------------------------------------------------------------------------
__global__ void __launch_bounds__(512, 2) k_gemmon(
    const u16* __restrict__ attb, const u16* __restrict__ wot,
    const float* __restrict__ biaso, const u16* __restrict__ nab,
    float* __restrict__ dout, int use_nab) {
  __shared__ u16 As[2][16384], Bs[2][16384];
  const int wg = (blockIdx.x & 7) * 64 + (blockIdx.x >> 3);    // 512 wgs
  const int mt = wg >> 2, nt = wg & 3;                         // nt-fastest
  float4v acc[8][4];
  ZERO_ACC8(acc);
  gemm8_core(attb + (size_t)mt * 256 * 1024, wot + (size_t)nt * 256 * 1024,
             As[0], As[1], Bs[0], Bs[1], acc);
  const int lane = threadIdx.x & 63, wid = threadIdx.x >> 6;
  const int wr = wid >> 2, wc = wid & 3;
  const int l15 = lane & 15, g = lane >> 4;
#pragma unroll
  for (int m = 0; m < 8; ++m) {
    const int rb = mt * 256 + wr * 128 + m * 16 + 4 * g;
#pragma unroll
    for (int j = 0; j < 4; ++j) {
      const int cg = nt * 256 + wc * 64 + j * 16 + l15;
      const float bia = biaso[cg];
      if (use_nab) {
#pragma unroll
        for (int r = 0; r < 4; ++r) {
          const size_t idx = (size_t)(rb + r) * 1024 + cg;
          const float v = bf2f(nab[idx]) + acc[m][j][r] + bia;
          __builtin_nontemporal_store(v, &dout[idx]);
        }
      } else {
#pragma unroll
        for (int r = 0; r < 4; ++r) {
          const size_t idx = (size_t)(rb + r) * 1024 + cg;
          const float v = dout[idx] + acc[m][j][r] + bia;
          __builtin_nontemporal_store(v, &dout[idx]);
        }
      }
    }
  }
}

// ---------------------------------------------------------------------------
extern "C" void kernel_launch(void* const* d_in, const int* in_sizes, int n_in,
                              void* d_out, int out_size, void* d_ws, size_t ws_size,
                              hipStream_t stream) {
  const float* x  = (const float*)d_in[0];
  const float* W1 = (const float*)d_in[1];
  const float* b1 = (const float*)d_in[2];
  const float* Wv = (const float*)d_in[3];
  const float* bv = (const float*)d_in[4];
  const float* Wo = (const float*)d_in[5];
  const float* bo = (const float*)d_in[6];
  float* out = (float*)d_out;

  const size_t N = 32768;
  u16* xb   = (u16*)d_ws;                       // x bf16 perm-k [N][1024]
  u16* qb   = xb  + N * 1024;                   // q (then att, perm-k)
  u16* ktb  = qb  + N * 1024;                   // k_t [8*128][N]
  u16* vtb  = ktb + N * 1024;                   // v_t [8*128][N]
  u16* wcat = vtb + N * 1024;                   // [W1|Wv]^T perm-k [4096][1024]
  u16* wot  = wcat + (size_t)4096 * 1024;       // Wo^T perm-k
  u16* part = wot + (size_t)1024 * 1024;        // kv partials bf16 [8][64][16384]
  u16* kvt  = part + (size_t)8 * 64 * 16384;    // kv_t [h][vd][kd]
  float* ksum = (float*)(kvt + (size_t)8 * 16384);    // [8][128]
  float* kspart = ksum + 1024;                        // [8][64][128]
  u16* nab  = (u16*)(kspart + (size_t)8 * 64 * 128);  // non_att bf16 (optional)
  const size_t need_nab = (size_t)((const char*)(nab + N * 1024) - (const char*)d_ws);
  const int use_nab = ws_size >= need_nab ? 1 : 0;

  k_conv<<<8192, 256, 0, stream>>>(x, xb);
  k_transpose<<<768, 256, 0, stream>>>(W1, wcat, 1024, 3072);
  k_transpose<<<256, 256, 0, stream>>>(Wv, wcat + (size_t)3072 * 1024, 1024, 1024);
  k_transpose<<<256, 256, 0, stream>>>(Wo, wot, 1024, 1024);
  k_gemm1n<<<1536, 512, 0, stream>>>(xb, wcat, b1, qb, ktb, nab, out, use_nab);
  k_gemm2n<<<512, 512, 0, stream>>>(xb, wcat + (size_t)3072 * 1024, bv, vtb);
  k_kvpart<<<512, 256, 0, stream>>>(ktb, vtb, part, kspart);
  k_kvred<<<1024, 128, 0, stream>>>(part, kspart, kvt, ksum);
  k_attn<<<2048, 256, 0, stream>>>(qb, kvt, ksum, qb);
  k_gemmon<<<512, 512, 0, stream>>>(qb, wot, bo, nab, out, use_nab);
}